// Round 1
// baseline (1863.921 us; speedup 1.0000x reference)
//
#include <hip/hip_runtime.h>

#define D 256
#define NC 64
#define NPC 1024

using u16 = unsigned short;
using u32 = unsigned int;

// skew to break LDS bank aliasing for 32-float-strided accesses
#define SK(c) ((c) + (((c) >> 5) << 2))

__device__ __forceinline__ float bf2f(u16 u) {
  union { u32 i; float f; } v; v.i = ((u32)u) << 16; return v.f;
}
__device__ __forceinline__ u16 f2bf(float f) {
  union { float f; u32 i; } v; v.f = f;
  u32 x = v.i;
  return (u16)((x + 0x7FFFu + ((x >> 16) & 1u)) >> 16);  // RTNE
}

// ---------------------------------------------------------------------------
// In-place Gauss-Jordan inverse of W (256x256), no pivoting.
// One block, 1024 threads: wave w owns rows 16w..16w+15, lane l owns cols 4l..4l+3.
// Pivot loop unrolled x16 so all register-array indices are compile-time.
// ---------------------------------------------------------------------------
__global__ __launch_bounds__(1024, 4) void gj_inverse(const float* __restrict__ W,
                                                      float* __restrict__ IW) {
  __shared__ float prow[256];
  const int t = threadIdx.x;
  const int w = t >> 6;
  const int l = t & 63;
  float x[16][4];
#pragma unroll
  for (int i = 0; i < 16; ++i) {
    float4 v = *(const float4*)(W + (16 * w + i) * D + 4 * l);
    x[i][0] = v.x; x[i][1] = v.y; x[i][2] = v.z; x[i][3] = v.w;
  }
  for (int pb = 0; pb < 16; ++pb) {
#pragma unroll
    for (int pi = 0; pi < 16; ++pi) {
      const int p = pb * 16 + pi;
      const int pq = p >> 2;     // lane owning column p
      const int pc = pi & 3;     // static (pi is literal)
      if (w == pb) {
        *(float4*)(&prow[4 * l]) = make_float4(x[pi][0], x[pi][1], x[pi][2], x[pi][3]);
      }
      __syncthreads();
      const float pv = prow[p];
      const float dinv = 1.0f / pv;
      const float4 prv = *(const float4*)(&prow[4 * l]);
      float uu[4] = {prv.x, prv.y, prv.z, prv.w};
      // extract column-p multipliers (must read BEFORE updates)
      float m[16];
#pragma unroll
      for (int i = 0; i < 16; ++i)
        m[i] = __int_as_float(__builtin_amdgcn_readlane(__float_as_int(x[i][pc]), pq));
      // in-place trick: u[p] := pv + 1 so the FMA writes -m*dinv into column p
      if (l == pq) uu[pc] += 1.0f;
#pragma unroll
      for (int i = 0; i < 16; ++i) {
        float mi = m[i] * dinv;
        if (i == pi) { if (w == pb) mi = 0.0f; }  // skip pivot row
        x[i][0] = fmaf(-mi, uu[0], x[i][0]);
        x[i][1] = fmaf(-mi, uu[1], x[i][1]);
        x[i][2] = fmaf(-mi, uu[2], x[i][2]);
        x[i][3] = fmaf(-mi, uu[3], x[i][3]);
      }
      if (w == pb) {  // scale pivot row; its column-p entry becomes dinv
        x[pi][0] = prv.x * dinv; x[pi][1] = prv.y * dinv;
        x[pi][2] = prv.z * dinv; x[pi][3] = prv.w * dinv;
        if (l == pq) x[pi][pc] = dinv;
      }
      __syncthreads();
    }
  }
#pragma unroll
  for (int i = 0; i < 16; ++i)
    *(float4*)(IW + (16 * w + i) * D + 4 * l) =
        make_float4(x[i][0], x[i][1], x[i][2], x[i][3]);
}

// ---------------------------------------------------------------------------
// Newton-Schulz refinement: R = 2I - W*X ; Y = X*R
// ---------------------------------------------------------------------------
__global__ __launch_bounds__(256) void nr_residual(const float* __restrict__ W,
                                                   const float* __restrict__ X,
                                                   float* __restrict__ R) {
  __shared__ float wrow[D];
  const int i = blockIdx.x, j = threadIdx.x;
  wrow[j] = W[i * D + j];
  __syncthreads();
  float acc = 0.f;
#pragma unroll 8
  for (int k = 0; k < D; ++k) acc = fmaf(wrow[k], X[k * D + j], acc);
  R[i * D + j] = (i == j ? 2.0f : 0.0f) - acc;
}

__global__ __launch_bounds__(256) void nr_mult(const float* __restrict__ X,
                                               const float* __restrict__ R,
                                               float* __restrict__ Y) {
  __shared__ float xrow[D];
  const int i = blockIdx.x, j = threadIdx.x;
  xrow[j] = X[i * D + j];
  __syncthreads();
  float acc = 0.f;
#pragma unroll 8
  for (int k = 0; k < D; ++k) acc = fmaf(xrow[k], R[k * D + j], acc);
  Y[i * D + j] = acc;
}

// ---------------------------------------------------------------------------
// Row squared-norms of protos1 / protos2. 4 rows per 256-thread block.
// ---------------------------------------------------------------------------
__global__ __launch_bounds__(256) void norms_in_kernel(const float* __restrict__ p1,
                                                       const float* __restrict__ p2,
                                                       float* __restrict__ n1,
                                                       float* __restrict__ n2) {
  const int t = threadIdx.x;
  const int lr = t >> 6;
  const int l = t & 63;
  const size_t g = (size_t)blockIdx.x * 4 + lr;
  float4 v = *(const float4*)(p1 + g * D + 4 * l);
  float s = fmaf(v.x, v.x, fmaf(v.y, v.y, fmaf(v.z, v.z, v.w * v.w)));
#pragma unroll
  for (int off = 32; off; off >>= 1) s += __shfl_xor(s, off, 64);
  if (l == 0) n1[g] = s;
  float4 u = *(const float4*)(p2 + g * D + 4 * l);
  float s2 = fmaf(u.x, u.x, fmaf(u.y, u.y, fmaf(u.z, u.z, u.w * u.w)));
#pragma unroll
  for (int off = 32; off; off >>= 1) s2 += __shfl_xor(s2, off, 64);
  if (l == 0) n2[g] = s2;
}

// ---------------------------------------------------------------------------
// Transform GEMM: Out[g][d] = sum_k Ain'[g][k] * Brows[d][k]  (+ bias if MODE 0)
//   MODE 0: F = p1 @ W^T + b      (Ain'=p1,    Brows=W)
//   MODE 1: Q = (p2 - b) @ IW^T   (Ain'=p2-b,  Brows=IW)
// Writes bf16 output and fp32 row norms. 64 rows per block, full N=256.
// ---------------------------------------------------------------------------
template <int MODE>
__global__ __launch_bounds__(256) void prep_kernel(const float* __restrict__ Ain,
                                                   const float* __restrict__ Brows,
                                                   const float* __restrict__ bias,
                                                   u16* __restrict__ Out,
                                                   float* __restrict__ norms) {
  __shared__ float As[16][68];
  __shared__ float Bs[16][288];
  const int tx = threadIdx.x;
  const int g0 = blockIdx.x * 64;
  const int rg = tx >> 4;   // row group: rows rg*4 .. rg*4+3
  const int td = tx & 15;   // col group: cols td*16 .. td*16+15
  float acc[4][16];
#pragma unroll
  for (int r = 0; r < 4; ++r)
#pragma unroll
    for (int e = 0; e < 16; ++e) acc[r][e] = 0.f;
  const int arow = tx >> 2;
  const int aks = (tx & 3) << 2;
  for (int kp = 0; kp < 16; ++kp) {
    float4 av = *(const float4*)(Ain + (size_t)(g0 + arow) * D + kp * 16 + aks);
    if (MODE == 1) {
      float4 bv = *(const float4*)(bias + kp * 16 + aks);
      av.x -= bv.x; av.y -= bv.y; av.z -= bv.z; av.w -= bv.w;
    }
    As[aks + 0][SK(arow)] = av.x;
    As[aks + 1][SK(arow)] = av.y;
    As[aks + 2][SK(arow)] = av.z;
    As[aks + 3][SK(arow)] = av.w;
    const float* brp = Brows + (size_t)tx * D + kp * 16;
#pragma unroll
    for (int q = 0; q < 4; ++q) {
      float4 bv = *(const float4*)(brp + q * 4);
      Bs[q * 4 + 0][SK(tx)] = bv.x;
      Bs[q * 4 + 1][SK(tx)] = bv.y;
      Bs[q * 4 + 2][SK(tx)] = bv.z;
      Bs[q * 4 + 3][SK(tx)] = bv.w;
    }
    __syncthreads();
#pragma unroll
    for (int k = 0; k < 16; ++k) {
      const float4 a = *(const float4*)(&As[k][SK(rg * 4)]);
      float b0[16];
#pragma unroll
      for (int q = 0; q < 4; ++q) {
        float4 bv = *(const float4*)(&Bs[k][SK(td * 16 + q * 4)]);
        b0[q * 4 + 0] = bv.x; b0[q * 4 + 1] = bv.y;
        b0[q * 4 + 2] = bv.z; b0[q * 4 + 3] = bv.w;
      }
#pragma unroll
      for (int e = 0; e < 16; ++e) {
        acc[0][e] = fmaf(a.x, b0[e], acc[0][e]);
        acc[1][e] = fmaf(a.y, b0[e], acc[1][e]);
        acc[2][e] = fmaf(a.z, b0[e], acc[2][e]);
        acc[3][e] = fmaf(a.w, b0[e], acc[3][e]);
      }
    }
    __syncthreads();
  }
  float biasr[16];
  if (MODE == 0) {
#pragma unroll
    for (int q = 0; q < 4; ++q) {
      float4 bv = *(const float4*)(bias + td * 16 + q * 4);
      biasr[q * 4 + 0] = bv.x; biasr[q * 4 + 1] = bv.y;
      biasr[q * 4 + 2] = bv.z; biasr[q * 4 + 3] = bv.w;
    }
  }
#pragma unroll
  for (int r = 0; r < 4; ++r) {
    const int g = g0 + rg * 4 + r;
    float vals[16];
    float ss = 0.f;
#pragma unroll
    for (int e = 0; e < 16; ++e) {
      float v = acc[r][e];
      if (MODE == 0) v += biasr[e];
      vals[e] = v;
      ss = fmaf(v, v, ss);
    }
#pragma unroll
    for (int off = 1; off < 16; off <<= 1) ss += __shfl_xor(ss, off, 64);
    if (td == 0) norms[g] = ss;
    u32 packed[8];
#pragma unroll
    for (int q = 0; q < 8; ++q)
      packed[q] = (u32)f2bf(vals[2 * q]) | ((u32)f2bf(vals[2 * q + 1]) << 16);
    *(uint4*)(Out + (size_t)g * D + td * 16) =
        make_uint4(packed[0], packed[1], packed[2], packed[3]);
    *(uint4*)(Out + (size_t)g * D + td * 16 + 8) =
        make_uint4(packed[4], packed[5], packed[6], packed[7]);
  }
}

// ---------------------------------------------------------------------------
// Distance + min kernel. Block = (class c, direction, i-tile of 128 rows).
// Loops all 8 j-tiles: 128x128xK=256 fp32 SGEMM (8x8 per thread) with fused
// dist = nA + nB - 2*dot and running min; per-block partial sum of 128 mins.
// ---------------------------------------------------------------------------
__global__ __launch_bounds__(256, 4) void dist_kernel(
    const float* __restrict__ p1, const float* __restrict__ p2,
    const u16* __restrict__ Qb, const u16* __restrict__ Fb,
    const float* __restrict__ n1, const float* __restrict__ n2,
    const float* __restrict__ nq, const float* __restrict__ nf,
    float* __restrict__ partial) {
  __shared__ float As[16][140];
  __shared__ float Bs[16][140];
  __shared__ float sums[16];
  const int bid = blockIdx.x;
  const int c = bid >> 4;
  const int dir = (bid >> 3) & 1;
  const int it = bid & 7;
  const float* Ain = dir ? p2 : p1;
  const u16* Bin = dir ? Fb : Qb;
  const float* nA = dir ? n2 : n1;
  const float* nB = dir ? nf : nq;
  const int tx = threadIdx.x;
  const int ti = tx >> 4, tj = tx & 15;
  const int il = tx >> 1;
  const int kh = (tx & 1) << 3;
  float na[8];
#pragma unroll
  for (int r = 0; r < 8; ++r)
    na[r] = nA[(size_t)(it * 128 + ti * 8 + r) * NC + c];
  float minv[8];
#pragma unroll
  for (int r = 0; r < 8; ++r) minv[r] = 3.0e38f;
  const float* aptr = Ain + ((size_t)(it * 128 + il) * NC + c) * D;
  for (int jt = 0; jt < 8; ++jt) {
    float acc[8][8];
#pragma unroll
    for (int r = 0; r < 8; ++r)
#pragma unroll
      for (int s2 = 0; s2 < 8; ++s2) acc[r][s2] = 0.f;
    const u16* bptr = Bin + ((size_t)(jt * 128 + il) * NC + c) * D;
    for (int kp = 0; kp < 16; ++kp) {
      {
        float4 a0 = *(const float4*)(aptr + kp * 16 + kh);
        float4 a1 = *(const float4*)(aptr + kp * 16 + kh + 4);
        const int s = SK(il);
        As[kh + 0][s] = a0.x; As[kh + 1][s] = a0.y;
        As[kh + 2][s] = a0.z; As[kh + 3][s] = a0.w;
        As[kh + 4][s] = a1.x; As[kh + 5][s] = a1.y;
        As[kh + 6][s] = a1.z; As[kh + 7][s] = a1.w;
      }
      {
        uint4 uv = *(const uint4*)(bptr + kp * 16 + kh);
        const int s = SK(il);
        Bs[kh + 0][s] = bf2f((u16)(uv.x & 0xFFFFu));
        Bs[kh + 1][s] = bf2f((u16)(uv.x >> 16));
        Bs[kh + 2][s] = bf2f((u16)(uv.y & 0xFFFFu));
        Bs[kh + 3][s] = bf2f((u16)(uv.y >> 16));
        Bs[kh + 4][s] = bf2f((u16)(uv.z & 0xFFFFu));
        Bs[kh + 5][s] = bf2f((u16)(uv.z >> 16));
        Bs[kh + 6][s] = bf2f((u16)(uv.w & 0xFFFFu));
        Bs[kh + 7][s] = bf2f((u16)(uv.w >> 16));
      }
      __syncthreads();
#pragma unroll
      for (int k = 0; k < 16; ++k) {
        const float4 av0 = *(const float4*)(&As[k][SK(ti * 8)]);
        const float4 av1 = *(const float4*)(&As[k][SK(ti * 8) + 4]);
        const float4 bv0 = *(const float4*)(&Bs[k][SK(tj * 8)]);
        const float4 bv1 = *(const float4*)(&Bs[k][SK(tj * 8) + 4]);
        const float a[8] = {av0.x, av0.y, av0.z, av0.w, av1.x, av1.y, av1.z, av1.w};
        const float b[8] = {bv0.x, bv0.y, bv0.z, bv0.w, bv1.x, bv1.y, bv1.z, bv1.w};
#pragma unroll
        for (int r = 0; r < 8; ++r)
#pragma unroll
          for (int s2 = 0; s2 < 8; ++s2)
            acc[r][s2] = fmaf(a[r], b[s2], acc[r][s2]);
      }
      __syncthreads();
    }
#pragma unroll
    for (int s2 = 0; s2 < 8; ++s2) {
      const int j = jt * 128 + tj * 8 + s2;
      const float nb = nB[(size_t)j * NC + c];
#pragma unroll
      for (int r = 0; r < 8; ++r) {
        const float dd = na[r] + nb - 2.0f * acc[r][s2];
        minv[r] = fminf(minv[r], dd);
      }
    }
  }
#pragma unroll
  for (int r = 0; r < 8; ++r) {
    float mm = minv[r];
#pragma unroll
    for (int off = 1; off < 16; off <<= 1) mm = fminf(mm, __shfl_xor(mm, off, 64));
    minv[r] = mm;
  }
  if (tj == 0) {
    float s = 0.f;
#pragma unroll
    for (int r = 0; r < 8; ++r) s += minv[r];
    sums[ti] = s;
  }
  __syncthreads();
  if (tx == 0) {
    float s = 0.f;
#pragma unroll
    for (int q = 0; q < 16; ++q) s += sums[q];
    partial[bid] = s;
  }
}

// ---------------------------------------------------------------------------
// partial[(c<<4)|(dir<<3)|it] -> out[dir*64 + c] = mean of mins
// ---------------------------------------------------------------------------
__global__ void finalize_kernel(const float* __restrict__ partial,
                                float* __restrict__ out) {
  const int tx = threadIdx.x;  // 0..127
  if (tx >= 128) return;
  const int dir = tx >> 6, c = tx & 63;
  float s = 0.f;
#pragma unroll
  for (int it = 0; it < 8; ++it) s += partial[(c << 4) | (dir << 3) | it];
  out[dir * 64 + c] = s * (1.0f / 1024.0f);
}

extern "C" void kernel_launch(void* const* d_in, const int* in_sizes, int n_in,
                              void* d_out, int out_size, void* d_ws, size_t ws_size,
                              hipStream_t stream) {
  const float* p1 = (const float*)d_in[0];
  const float* p2 = (const float*)d_in[1];
  const float* W  = (const float*)d_in[2];
  const float* bv = (const float*)d_in[3];
  float* out = (float*)d_out;
  char* ws = (char*)d_ws;
  float* IWa = (float*)(ws + 0);                 // 256 KB
  float* Rt  = (float*)(ws + (256 << 10));       // 256 KB
  float* IWb = (float*)(ws + (512 << 10));       // 256 KB
  float* n1  = (float*)(ws + (768 << 10));       // 256 KB
  float* n2  = (float*)(ws + (1024 << 10));
  float* nq  = (float*)(ws + (1280 << 10));
  float* nf  = (float*)(ws + (1536 << 10));
  float* partial = (float*)(ws + (1792 << 10));  // 4 KB
  u16* Fbuf = (u16*)(ws + (2048 << 10));                  // 32 MB
  u16* Qbuf = (u16*)(ws + (2048 << 10) + (32u << 20));    // 32 MB

  // independent of the inverse: input norms + forward transform F
  norms_in_kernel<<<16384, 256, 0, stream>>>(p1, p2, n1, n2);
  prep_kernel<0><<<1024, 256, 0, stream>>>(p1, W, bv, Fbuf, nf);
  // inverse of W + two Newton-Schulz refinements
  gj_inverse<<<1, 1024, 0, stream>>>(W, IWa);
  nr_residual<<<256, 256, 0, stream>>>(W, IWa, Rt);
  nr_mult<<<256, 256, 0, stream>>>(IWa, Rt, IWb);
  nr_residual<<<256, 256, 0, stream>>>(W, IWb, Rt);
  nr_mult<<<256, 256, 0, stream>>>(IWb, Rt, IWa);
  // Q = (p2 - b) @ inv(W)^T
  prep_kernel<1><<<1024, 256, 0, stream>>>(p2, IWa, bv, Qbuf, nq);
  // fused pairwise-distance + min + partial mean
  dist_kernel<<<1024, 256, 0, stream>>>(p1, p2, Qbuf, Fbuf, n1, n2, nq, nf, partial);
  finalize_kernel<<<1, 128, 0, stream>>>(partial, out);
}

// Round 2
// 927.022 us; speedup vs baseline: 2.0107x; 2.0107x over previous
//
#include <hip/hip_runtime.h>

#define D 256
#define NC 64

using u16 = unsigned short;
using u32 = unsigned int;

typedef __attribute__((ext_vector_type(8))) short bfv8;   // 8 bf16 = 16 B
typedef __attribute__((ext_vector_type(4))) float f32x4;

__device__ __forceinline__ float bf2f(u32 u) {
  union { u32 i; float f; } v; v.i = u << 16; return v.f;
}
__device__ __forceinline__ u16 f2bf(float f) {
  union { float f; u32 i; } v; v.f = f;
  u32 x = v.i;
  return (u16)((x + 0x7FFFu + ((x >> 16) & 1u)) >> 16);  // RTNE
}
__device__ __forceinline__ u32 pk2(float a, float b) {
  return (u32)f2bf(a) | ((u32)f2bf(b) << 16);
}

__device__ __forceinline__ void gload_lds16(const void* src, void* dst) {
  __builtin_amdgcn_global_load_lds(
      (const __attribute__((address_space(1))) void*)src,
      (__attribute__((address_space(3))) void*)dst, 16, 0, 0);
}

// ---------------------------------------------------------------------------
// Gauss-Jordan inverse of W (256x256), verified in round 1.
// ---------------------------------------------------------------------------
__global__ __launch_bounds__(1024, 4) void gj_inverse(const float* __restrict__ W,
                                                      float* __restrict__ IW) {
  __shared__ float prow[256];
  const int t = threadIdx.x;
  const int w = t >> 6;
  const int l = t & 63;
  float x[16][4];
#pragma unroll
  for (int i = 0; i < 16; ++i) {
    float4 v = *(const float4*)(W + (16 * w + i) * D + 4 * l);
    x[i][0] = v.x; x[i][1] = v.y; x[i][2] = v.z; x[i][3] = v.w;
  }
  for (int pb = 0; pb < 16; ++pb) {
#pragma unroll
    for (int pi = 0; pi < 16; ++pi) {
      const int p = pb * 16 + pi;
      const int pq = p >> 2;
      const int pc = pi & 3;
      if (w == pb) {
        *(float4*)(&prow[4 * l]) = make_float4(x[pi][0], x[pi][1], x[pi][2], x[pi][3]);
      }
      __syncthreads();
      const float pv = prow[p];
      const float dinv = 1.0f / pv;
      const float4 prv = *(const float4*)(&prow[4 * l]);
      float uu[4] = {prv.x, prv.y, prv.z, prv.w};
      float m[16];
#pragma unroll
      for (int i = 0; i < 16; ++i)
        m[i] = __int_as_float(__builtin_amdgcn_readlane(__float_as_int(x[i][pc]), pq));
      if (l == pq) uu[pc] += 1.0f;
#pragma unroll
      for (int i = 0; i < 16; ++i) {
        float mi = m[i] * dinv;
        if (i == pi) { if (w == pb) mi = 0.0f; }
        x[i][0] = fmaf(-mi, uu[0], x[i][0]);
        x[i][1] = fmaf(-mi, uu[1], x[i][1]);
        x[i][2] = fmaf(-mi, uu[2], x[i][2]);
        x[i][3] = fmaf(-mi, uu[3], x[i][3]);
      }
      if (w == pb) {
        x[pi][0] = prv.x * dinv; x[pi][1] = prv.y * dinv;
        x[pi][2] = prv.z * dinv; x[pi][3] = prv.w * dinv;
        if (l == pq) x[pi][pc] = dinv;
      }
      __syncthreads();
    }
  }
#pragma unroll
  for (int i = 0; i < 16; ++i)
    *(float4*)(IW + (16 * w + i) * D + 4 * l) =
        make_float4(x[i][0], x[i][1], x[i][2], x[i][3]);
}

__global__ __launch_bounds__(256) void nr_residual(const float* __restrict__ W,
                                                   const float* __restrict__ X,
                                                   float* __restrict__ R) {
  __shared__ float wrow[D];
  const int i = blockIdx.x, j = threadIdx.x;
  wrow[j] = W[i * D + j];
  __syncthreads();
  float acc = 0.f;
#pragma unroll 8
  for (int k = 0; k < D; ++k) acc = fmaf(wrow[k], X[k * D + j], acc);
  R[i * D + j] = (i == j ? 2.0f : 0.0f) - acc;
}

__global__ __launch_bounds__(256) void nr_mult(const float* __restrict__ X,
                                               const float* __restrict__ R,
                                               float* __restrict__ Y) {
  __shared__ float xrow[D];
  const int i = blockIdx.x, j = threadIdx.x;
  xrow[j] = X[i * D + j];
  __syncthreads();
  float acc = 0.f;
#pragma unroll 8
  for (int k = 0; k < D; ++k) acc = fmaf(xrow[k], R[k * D + j], acc);
  Y[i * D + j] = acc;
}

// ---------------------------------------------------------------------------
// W -> bf16
// ---------------------------------------------------------------------------
__global__ __launch_bounds__(256) void wconv(const float* __restrict__ W,
                                             u16* __restrict__ Wb) {
  const int i = blockIdx.x * 256 + threadIdx.x;
  Wb[i] = f2bf(W[i]);
}

// IW -> bf16, and bneg[col] = -(b . IW[col][:])
__global__ __launch_bounds__(256) void iwconv_bneg(const float* __restrict__ IW,
                                                   const float* __restrict__ bv,
                                                   u16* __restrict__ IWb,
                                                   float* __restrict__ bneg) {
  __shared__ float ws4[4];
  const int col = blockIdx.x, t = threadIdx.x;
  const float v = IW[col * D + t];
  IWb[col * D + t] = f2bf(v);
  float s = v * bv[t];
#pragma unroll
  for (int off = 32; off; off >>= 1) s += __shfl_xor(s, off, 64);
  if ((t & 63) == 0) ws4[t >> 6] = s;
  __syncthreads();
  if (t == 0) bneg[col] = -(ws4[0] + ws4[1] + ws4[2] + ws4[3]);
}

// ---------------------------------------------------------------------------
// Row squared-norms of p1/p2 (exact f32), written CLASS-MAJOR: n[c*1024+i].
// ---------------------------------------------------------------------------
__global__ __launch_bounds__(256) void norms12(const float* __restrict__ p1,
                                               const float* __restrict__ p2,
                                               float* __restrict__ n1,
                                               float* __restrict__ n2) {
  const int t = threadIdx.x, lr = t >> 6, l = t & 63;
  const size_t g = (size_t)blockIdx.x * 4 + lr;
  const size_t ci = ((g & 63) << 10) + (g >> 6);
  float4 v = *(const float4*)(p1 + g * D + l * 4);
  float s = fmaf(v.x, v.x, fmaf(v.y, v.y, fmaf(v.z, v.z, v.w * v.w)));
#pragma unroll
  for (int off = 32; off; off >>= 1) s += __shfl_xor(s, off, 64);
  if (l == 0) n1[ci] = s;
  float4 u = *(const float4*)(p2 + g * D + l * 4);
  float s2 = fmaf(u.x, u.x, fmaf(u.y, u.y, fmaf(u.z, u.z, u.w * u.w)));
#pragma unroll
  for (int off = 32; off; off >>= 1) s2 += __shfl_xor(s2, off, 64);
  if (l == 0) n2[ci] = s2;
}

// Row squared-norms of the bf16 F/Q buffers (already class-major).
__global__ __launch_bounds__(256) void norms_fq(const u16* __restrict__ Fb,
                                                const u16* __restrict__ Qb,
                                                float* __restrict__ nf,
                                                float* __restrict__ nq) {
  const int t = threadIdx.x, lr = t >> 6, l = t & 63;
  const size_t m = (size_t)blockIdx.x * 4 + lr;
  uint2 a = *(const uint2*)(Fb + m * D + l * 4);
  float x0 = bf2f(a.x & 0xFFFFu), x1 = bf2f(a.x >> 16);
  float x2 = bf2f(a.y & 0xFFFFu), x3 = bf2f(a.y >> 16);
  float s = fmaf(x0, x0, fmaf(x1, x1, fmaf(x2, x2, x3 * x3)));
#pragma unroll
  for (int off = 32; off; off >>= 1) s += __shfl_xor(s, off, 64);
  if (l == 0) nf[m] = s;
  uint2 b = *(const uint2*)(Qb + m * D + l * 4);
  float y0 = bf2f(b.x & 0xFFFFu), y1 = bf2f(b.x >> 16);
  float y2 = bf2f(b.y & 0xFFFFu), y3 = bf2f(b.y >> 16);
  float s2 = fmaf(y0, y0, fmaf(y1, y1, fmaf(y2, y2, y3 * y3)));
#pragma unroll
  for (int off = 32; off; off >>= 1) s2 += __shfl_xor(s2, off, 64);
  if (l == 0) nq[m] = s2;
}

// ---------------------------------------------------------------------------
// prep (MFMA): Out = bf16(A) @ Brows^T + bias, written CLASS-MAJOR bf16.
//   MODE 0: A=p1, Brows=Wb,  bias=b     -> F
//   MODE 1: A=p2, Brows=IWb, bias=bneg  -> Q   (bneg = -b@IW^T folds the -b)
// Block = 128 original rows x 128 cols. LDS: A 64KB + B 64KB, fragment-ordered.
// ---------------------------------------------------------------------------
#define PREP_LDS 131072
template <int MODE>
__global__ __launch_bounds__(256) void prep_kernel(const float* __restrict__ Ain,
                                                   const u16* __restrict__ Brows,
                                                   const float* __restrict__ bias,
                                                   u16* __restrict__ Out) {
  extern __shared__ char smem[];
  const int bid = blockIdx.x;
  const int it = bid >> 1, jh = bid & 1;
  const int tx = threadIdx.x, wid = tx >> 6, l = tx & 63;
  const int wm = wid >> 1, wn = wid & 1, l4 = l >> 4, lm = l & 15;

  // B staging: 64 chunks of 1KB, fragment order, via global_load_lds
#pragma unroll
  for (int u = 0; u < 16; ++u) {
    const int ks = wid * 2 + (u >> 3), jf = u & 7;
    const u16* src = Brows + (size_t)(jh * 128 + jf * 16 + lm) * D + ks * 32 + l4 * 8;
    gload_lds16(src, smem + 65536 + (ks * 8 + jf) * 1024);
  }
  // A staging: f32 -> bf16 convert, fragment order
  {
    const int r = tx >> 1, h = tx & 1;
    const float* arow = Ain + (size_t)(it * 128 + r) * D + h * 128;
#pragma unroll
    for (int q = 0; q < 4; ++q) {
      const int ks = h * 4 + q;
#pragma unroll
      for (int g = 0; g < 4; ++g) {
        float4 v0 = *(const float4*)(arow + q * 32 + g * 8);
        float4 v1 = *(const float4*)(arow + q * 32 + g * 8 + 4);
        uint4 w;
        w.x = pk2(v0.x, v0.y); w.y = pk2(v0.z, v0.w);
        w.z = pk2(v1.x, v1.y); w.w = pk2(v1.z, v1.w);
        *(uint4*)(smem + (ks * 8 + (r >> 4)) * 1024 + ((r & 15) + g * 16) * 16) = w;
      }
    }
  }
  __syncthreads();

  const bfv8* lds8 = (const bfv8*)smem;
  f32x4 acc[4][4];
#pragma unroll
  for (int m = 0; m < 4; ++m)
#pragma unroll
    for (int n = 0; n < 4; ++n) acc[m][n] = f32x4{0.f, 0.f, 0.f, 0.f};
#pragma unroll
  for (int ks = 0; ks < 8; ++ks) {
    bfv8 a[4], bb[4];
#pragma unroll
    for (int m = 0; m < 4; ++m) a[m] = lds8[(ks * 8 + wm * 4 + m) * 64 + l];
#pragma unroll
    for (int n = 0; n < 4; ++n) bb[n] = lds8[4096 + (ks * 8 + wn * 4 + n) * 64 + l];
#pragma unroll
    for (int m = 0; m < 4; ++m)
#pragma unroll
      for (int n = 0; n < 4; ++n)
        acc[m][n] = __builtin_amdgcn_mfma_f32_16x16x32_bf16(a[m], bb[n], acc[m][n], 0, 0, 0);
  }

  float bvv[4];
#pragma unroll
  for (int n = 0; n < 4; ++n) bvv[n] = bias[jh * 128 + wn * 64 + n * 16 + lm];
#pragma unroll
  for (int m = 0; m < 4; ++m)
#pragma unroll
    for (int rr = 0; rr < 4; ++rr) {
      const int g = it * 128 + wm * 64 + m * 16 + l4 * 4 + rr;
      const size_t orow = (size_t)(((g & 63) << 10) | (g >> 6)) * D;
#pragma unroll
      for (int n = 0; n < 4; ++n) {
        const int col = jh * 128 + wn * 64 + n * 16 + lm;
        Out[orow + col] = f2bf(acc[m][n][rr] + bvv[n]);
      }
    }
}

// ---------------------------------------------------------------------------
// dist (MFMA): per (c, dir, i-tile 128): loop 8 j-tiles of 128, K=256 bf16
// MFMA GEMM; fused dist = na+nb-2*dot and running min; block-partial sums.
// LDS: A 64KB (once) + B two 32KB half-K buffers (double-buffered) + reduce.
// ---------------------------------------------------------------------------
#define DIST_LDS 132160
__global__ __launch_bounds__(256) void dist_kernel(
    const float* __restrict__ p1, const float* __restrict__ p2,
    const u16* __restrict__ Qb, const u16* __restrict__ Fb,
    const float* __restrict__ n1, const float* __restrict__ n2,
    const float* __restrict__ nq, const float* __restrict__ nf,
    float* __restrict__ partial) {
  extern __shared__ char smem[];
  const int bid = blockIdx.x;
  const int lb = (bid & 7) * 128 + (bid >> 3);   // XCD-chunked swizzle
  const int c = lb >> 4, dir = (lb >> 3) & 1, it = lb & 7;
  const float* Ain = dir ? p2 : p1;
  const u16* Bin = dir ? Fb : Qb;
  const float* nA = dir ? n2 : n1;
  const float* nB = dir ? nf : nq;
  const int tx = threadIdx.x, wid = tx >> 6, l = tx & 63;
  const int wm = wid >> 1, wn = wid & 1, l4 = l >> 4, lm = l & 15;

  auto issue_b = [&](int half, int jt) {
    const size_t base = ((size_t)(c << 10) + jt * 128) * D;
#pragma unroll
    for (int jf = 0; jf < 8; ++jf) {
      const u16* src = Bin + base + (size_t)(jf * 16 + lm) * D
                       + half * 128 + wid * 32 + l4 * 8;
      gload_lds16(src, smem + 65536 + half * 32768 + (wid * 8 + jf) * 1024);
    }
  };

  issue_b(0, 0);
  // A staging (f32 gather, strided by class; convert to bf16 fragments)
  {
    const int r = tx >> 1, h = tx & 1;
    const float* arow = Ain + ((size_t)(it * 128 + r) * NC + c) * D + h * 128;
#pragma unroll
    for (int q = 0; q < 4; ++q) {
      const int ks = h * 4 + q;
#pragma unroll
      for (int g = 0; g < 4; ++g) {
        float4 v0 = *(const float4*)(arow + q * 32 + g * 8);
        float4 v1 = *(const float4*)(arow + q * 32 + g * 8 + 4);
        uint4 w;
        w.x = pk2(v0.x, v0.y); w.y = pk2(v0.z, v0.w);
        w.z = pk2(v1.x, v1.y); w.w = pk2(v1.z, v1.w);
        *(uint4*)(smem + (ks * 8 + (r >> 4)) * 1024 + ((r & 15) + g * 16) * 16) = w;
      }
    }
  }
  float na[4][4];
#pragma unroll
  for (int m = 0; m < 4; ++m)
#pragma unroll
    for (int rr = 0; rr < 4; ++rr)
      na[m][rr] = nA[(c << 10) + it * 128 + wm * 64 + m * 16 + l4 * 4 + rr];
  float minv[4][4];
#pragma unroll
  for (int m = 0; m < 4; ++m)
#pragma unroll
    for (int rr = 0; rr < 4; ++rr) minv[m][rr] = 3.0e38f;
  __syncthreads();

  const bfv8* lds8 = (const bfv8*)smem;
  for (int jt = 0; jt < 8; ++jt) {
    f32x4 acc[4][4];
#pragma unroll
    for (int m = 0; m < 4; ++m)
#pragma unroll
      for (int n = 0; n < 4; ++n) acc[m][n] = f32x4{0.f, 0.f, 0.f, 0.f};
    float nbv[4];
#pragma unroll
    for (int n = 0; n < 4; ++n)
      nbv[n] = nB[(c << 10) + jt * 128 + wn * 64 + n * 16 + lm];

    // phase 0: compute ksteps 0-3 from B0 while B1(jt) loads
    issue_b(1, jt);
#pragma unroll
    for (int ks = 0; ks < 4; ++ks) {
      bfv8 a[4], bb[4];
#pragma unroll
      for (int m = 0; m < 4; ++m) a[m] = lds8[(ks * 8 + wm * 4 + m) * 64 + l];
#pragma unroll
      for (int n = 0; n < 4; ++n) bb[n] = lds8[4096 + (ks * 8 + wn * 4 + n) * 64 + l];
#pragma unroll
      for (int m = 0; m < 4; ++m)
#pragma unroll
        for (int n = 0; n < 4; ++n)
          acc[m][n] = __builtin_amdgcn_mfma_f32_16x16x32_bf16(a[m], bb[n], acc[m][n], 0, 0, 0);
    }
    __syncthreads();
    // phase 1: compute ksteps 4-7 from B1 while B0(jt+1) loads
    if (jt < 7) issue_b(0, jt + 1);
#pragma unroll
    for (int ks = 4; ks < 8; ++ks) {
      bfv8 a[4], bb[4];
#pragma unroll
      for (int m = 0; m < 4; ++m) a[m] = lds8[(ks * 8 + wm * 4 + m) * 64 + l];
#pragma unroll
      for (int n = 0; n < 4; ++n)
        bb[n] = lds8[6144 + ((ks - 4) * 8 + wn * 4 + n) * 64 + l];
#pragma unroll
      for (int m = 0; m < 4; ++m)
#pragma unroll
        for (int n = 0; n < 4; ++n)
          acc[m][n] = __builtin_amdgcn_mfma_f32_16x16x32_bf16(a[m], bb[n], acc[m][n], 0, 0, 0);
    }
    // fused distance + min epilogue (registers only)
#pragma unroll
    for (int m = 0; m < 4; ++m)
#pragma unroll
      for (int n = 0; n < 4; ++n)
#pragma unroll
        for (int rr = 0; rr < 4; ++rr) {
          const float dd = na[m][rr] + nbv[n] - 2.0f * acc[m][n][rr];
          minv[m][rr] = fminf(minv[m][rr], dd);
        }
    __syncthreads();
  }

  // reduce: min over the 16 col-lanes, then across the two wn waves, then sum
  float* red = (float*)(smem + 131072);
#pragma unroll
  for (int m = 0; m < 4; ++m)
#pragma unroll
    for (int rr = 0; rr < 4; ++rr) {
      float mm = minv[m][rr];
      mm = fminf(mm, __shfl_xor(mm, 1, 64));
      mm = fminf(mm, __shfl_xor(mm, 2, 64));
      mm = fminf(mm, __shfl_xor(mm, 4, 64));
      mm = fminf(mm, __shfl_xor(mm, 8, 64));
      if (lm == 0) red[wn * 128 + wm * 64 + m * 16 + l4 * 4 + rr] = mm;
    }
  __syncthreads();
  if (tx < 128) {
    float v = fminf(red[tx], red[128 + tx]);
#pragma unroll
    for (int off = 32; off; off >>= 1) v += __shfl_xor(v, off, 64);
    if ((tx & 63) == 0) red[256 + (tx >> 6)] = v;
  }
  __syncthreads();
  if (tx == 0) partial[lb] = red[256] + red[257];
}

__global__ void finalize_kernel(const float* __restrict__ partial,
                                float* __restrict__ out) {
  const int tx = threadIdx.x;
  if (tx >= 128) return;
  const int dir = tx >> 6, c = tx & 63;
  float s = 0.f;
#pragma unroll
  for (int it = 0; it < 8; ++it) s += partial[(c << 4) | (dir << 3) | it];
  out[dir * 64 + c] = s * (1.0f / 1024.0f);
}

extern "C" void kernel_launch(void* const* d_in, const int* in_sizes, int n_in,
                              void* d_out, int out_size, void* d_ws, size_t ws_size,
                              hipStream_t stream) {
  const float* p1 = (const float*)d_in[0];
  const float* p2 = (const float*)d_in[1];
  const float* W  = (const float*)d_in[2];
  const float* bv = (const float*)d_in[3];
  float* out = (float*)d_out;
  char* ws = (char*)d_ws;
  float* IWa  = (float*)(ws + 0);                // 256 KB
  float* Rt   = (float*)(ws + (256 << 10));      // 256 KB
  float* IWc  = (float*)(ws + (512 << 10));      // 256 KB
  float* n1   = (float*)(ws + (768 << 10));      // 256 KB each
  float* n2   = (float*)(ws + (1024 << 10));
  float* nq   = (float*)(ws + (1280 << 10));
  float* nf   = (float*)(ws + (1536 << 10));
  float* partial = (float*)(ws + (1792 << 10));  // 4 KB
  float* bneg = (float*)(ws + (1800 << 10));     // 1 KB
  u16* Wb  = (u16*)(ws + (1808 << 10));          // 128 KB
  u16* IWb = (u16*)(ws + (1936 << 10));          // 128 KB
  u16* Fb  = (u16*)(ws + (2112 << 10));                  // 32 MB
  u16* Qb  = (u16*)(ws + (2112 << 10) + (32u << 20));    // 32 MB

  hipFuncSetAttribute((const void*)prep_kernel<0>,
                      hipFuncAttributeMaxDynamicSharedMemorySize, PREP_LDS);
  hipFuncSetAttribute((const void*)prep_kernel<1>,
                      hipFuncAttributeMaxDynamicSharedMemorySize, PREP_LDS);
  hipFuncSetAttribute((const void*)dist_kernel,
                      hipFuncAttributeMaxDynamicSharedMemorySize, DIST_LDS);

  norms12<<<16384, 256, 0, stream>>>(p1, p2, n1, n2);
  wconv<<<256, 256, 0, stream>>>(W, Wb);
  gj_inverse<<<1, 1024, 0, stream>>>(W, IWa);
  nr_residual<<<256, 256, 0, stream>>>(W, IWa, Rt);
  nr_mult<<<256, 256, 0, stream>>>(IWa, Rt, IWc);
  nr_residual<<<256, 256, 0, stream>>>(W, IWc, Rt);
  nr_mult<<<256, 256, 0, stream>>>(IWc, Rt, IWa);
  iwconv_bneg<<<256, 256, 0, stream>>>(IWa, bv, IWb, bneg);
  prep_kernel<0><<<1024, 256, PREP_LDS, stream>>>(p1, Wb, bv, Fb);
  prep_kernel<1><<<1024, 256, PREP_LDS, stream>>>(p2, IWb, bneg, Qb);
  norms_fq<<<16384, 256, 0, stream>>>(Fb, Qb, nf, nq);
  dist_kernel<<<1024, 256, DIST_LDS, stream>>>(p1, p2, Qb, Fb, n1, n2, nq, nf, partial);
  finalize_kernel<<<1, 128, 0, stream>>>(partial, out);
}

// Round 3
// 483.497 us; speedup vs baseline: 3.8551x; 1.9173x over previous
//
#include <hip/hip_runtime.h>

#define D 256
#define NC 64

using u16 = unsigned short;
using u32 = unsigned int;

typedef __attribute__((ext_vector_type(8))) short bfv8;   // 8 bf16 = 16 B
typedef __attribute__((ext_vector_type(4))) float f32x4;

__device__ __forceinline__ float bf2f(u32 u) {
  union { u32 i; float f; } v; v.i = u << 16; return v.f;
}
__device__ __forceinline__ u16 f2bf(float f) {
  union { float f; u32 i; } v; v.f = f;
  u32 x = v.i;
  return (u16)((x + 0x7FFFu + ((x >> 16) & 1u)) >> 16);  // RTNE
}
__device__ __forceinline__ u32 pk2(float a, float b) {
  return (u32)f2bf(a) | ((u32)f2bf(b) << 16);
}

__device__ __forceinline__ void gload_lds16(const void* src, void* dst) {
  __builtin_amdgcn_global_load_lds(
      (const __attribute__((address_space(1))) void*)src,
      (__attribute__((address_space(3))) void*)dst, 16, 0, 0);
}

// ---------------------------------------------------------------------------
// Blocked Gauss-Jordan inverse of W (256x256), NB=16, no pivoting.
// One block, 512 threads (8 waves): wave w owns rows 32w..32w+31, lane l owns
// cols 4l..4l+3 (x[32][4] in VGPRs). Per block-step: stage panel cols M and
// panel rows to LDS; wave 0 inverts the 16x16 pivot block wave-synchronously
// (readlane, no barriers); all waves compute G = Pinv*A[C,:]; rank-16 update
// x -= M*G. 64 barriers total (vs 512 in the rank-1 version).
// ---------------------------------------------------------------------------
__global__ __launch_bounds__(512, 2) void gj_inverse(const float* __restrict__ W,
                                                     float* __restrict__ IW) {
  __shared__ float Ml[256][20];    // current panel columns (padded stride 20)
  __shared__ float Arow[16][256];  // current panel rows (pre-update)
  __shared__ float G[16][256];     // Pinv * A[C,:]  (C-cols hold I+Pinv)
  __shared__ float Pinv[16][20];
  const int t = threadIdx.x, w = t >> 6, l = t & 63;
  float x[32][4];
#pragma unroll
  for (int i = 0; i < 32; ++i) {
    float4 v = *(const float4*)(W + (size_t)(32 * w + i) * D + 4 * l);
    x[i][0] = v.x; x[i][1] = v.y; x[i][2] = v.z; x[i][3] = v.w;
  }
  for (int s = 0; s < 16; ++s) {
    const int pw = s >> 1, ph = s & 1;
    const bool inC = ((l >> 2) == s);
    const int co = (l & 3) << 2;
    // 1) stage panel columns M; pivot wave stages its 16 panel rows
    if (inC) {
#pragma unroll
      for (int i = 0; i < 32; ++i)
        *(float4*)&Ml[32 * w + i][co] =
            make_float4(x[i][0], x[i][1], x[i][2], x[i][3]);
    }
    if (w == pw) {
      if (ph == 0) {
#pragma unroll
        for (int q = 0; q < 16; ++q)
          *(float4*)&Arow[q][4 * l] =
              make_float4(x[q][0], x[q][1], x[q][2], x[q][3]);
      } else {
#pragma unroll
        for (int q = 0; q < 16; ++q)
          *(float4*)&Arow[q][4 * l] =
              make_float4(x[16 + q][0], x[16 + q][1], x[16 + q][2], x[16 + q][3]);
      }
    }
    __syncthreads();
    // 2) wave 0 lanes 0..15: invert 16x16 pivot block P (wave-synchronous GJ)
    if (t < 16) {
      float p[16];
      {
        float4 r0 = *(const float4*)&Ml[16 * s + t][0];
        float4 r1 = *(const float4*)&Ml[16 * s + t][4];
        float4 r2 = *(const float4*)&Ml[16 * s + t][8];
        float4 r3 = *(const float4*)&Ml[16 * s + t][12];
        p[0] = r0.x; p[1] = r0.y; p[2] = r0.z; p[3] = r0.w;
        p[4] = r1.x; p[5] = r1.y; p[6] = r1.z; p[7] = r1.w;
        p[8] = r2.x; p[9] = r2.y; p[10] = r2.z; p[11] = r2.w;
        p[12] = r3.x; p[13] = r3.y; p[14] = r3.z; p[15] = r3.w;
      }
#pragma unroll
      for (int pp = 0; pp < 16; ++pp) {
        float u[16];
#pragma unroll
        for (int j = 0; j < 16; ++j)
          u[j] = __int_as_float(__builtin_amdgcn_readlane(__float_as_int(p[j]), pp));
        const float pv = u[pp];
        const float d = 1.0f / pv;
        if (t == pp) {
#pragma unroll
          for (int j = 0; j < 16; ++j) p[j] = u[j] * d;
          p[pp] = d;
        } else {
          const float md = p[pp] * d;
          u[pp] = pv + 1.0f;  // in-place trick: column pp becomes -m*d
#pragma unroll
          for (int j = 0; j < 16; ++j) p[j] = fmaf(-md, u[j], p[j]);
        }
      }
#pragma unroll
      for (int j = 0; j < 16; ++j) Pinv[t][j] = p[j];
    }
    __syncthreads();
    // 3) G = Pinv * Arow ; wave w computes G rows 2w, 2w+1
#pragma unroll
    for (int h = 0; h < 2; ++h) {
      const int kk = 2 * w + h;
      float4 g = make_float4(0.f, 0.f, 0.f, 0.f);
#pragma unroll
      for (int q = 0; q < 16; ++q) {
        const float pv = Pinv[kk][q];
        const float4 av = *(const float4*)&Arow[q][4 * l];
        g.x = fmaf(pv, av.x, g.x); g.y = fmaf(pv, av.y, g.y);
        g.z = fmaf(pv, av.z, g.z); g.w = fmaf(pv, av.w, g.w);
      }
      if (inC) {  // C-columns: store I + Pinv (for the rank-16 update)
        g.x = Pinv[kk][co + 0] + (kk == co + 0 ? 1.f : 0.f);
        g.y = Pinv[kk][co + 1] + (kk == co + 1 ? 1.f : 0.f);
        g.z = Pinv[kk][co + 2] + (kk == co + 2 ? 1.f : 0.f);
        g.w = Pinv[kk][co + 3] + (kk == co + 3 ? 1.f : 0.f);
      }
      *(float4*)&G[kk][4 * l] = g;
    }
    __syncthreads();
    // 4) rank-16 update (non-pivot rows) + readback (pivot rows)
#pragma unroll
    for (int hh = 0; hh < 2; ++hh) {
      float4 Gv[8];
#pragma unroll
      for (int k8 = 0; k8 < 8; ++k8)
        Gv[k8] = *(const float4*)&G[hh * 8 + k8][4 * l];
#pragma unroll
      for (int i = 0; i < 32; ++i) {
        const bool piv = (w == pw) && ((i >> 4) == ph);
        if (piv) {
          if (hh == 0) {
            const int q = i & 15;
            if (inC) {
              x[i][0] = Pinv[q][co + 0]; x[i][1] = Pinv[q][co + 1];
              x[i][2] = Pinv[q][co + 2]; x[i][3] = Pinv[q][co + 3];
            } else {
              const float4 g = *(const float4*)&G[q][4 * l];
              x[i][0] = g.x; x[i][1] = g.y; x[i][2] = g.z; x[i][3] = g.w;
            }
          }
        } else {
          const float4 m0 = *(const float4*)&Ml[32 * w + i][hh * 8];
          const float4 m1 = *(const float4*)&Ml[32 * w + i][hh * 8 + 4];
          const float mm[8] = {m0.x, m0.y, m0.z, m0.w, m1.x, m1.y, m1.z, m1.w};
#pragma unroll
          for (int k8 = 0; k8 < 8; ++k8) {
            x[i][0] = fmaf(-mm[k8], Gv[k8].x, x[i][0]);
            x[i][1] = fmaf(-mm[k8], Gv[k8].y, x[i][1]);
            x[i][2] = fmaf(-mm[k8], Gv[k8].z, x[i][2]);
            x[i][3] = fmaf(-mm[k8], Gv[k8].w, x[i][3]);
          }
        }
      }
    }
    __syncthreads();
  }
#pragma unroll
  for (int i = 0; i < 32; ++i)
    *(float4*)(IW + (size_t)(32 * w + i) * D + 4 * l) =
        make_float4(x[i][0], x[i][1], x[i][2], x[i][3]);
}

__global__ __launch_bounds__(256) void nr_residual(const float* __restrict__ W,
                                                   const float* __restrict__ X,
                                                   float* __restrict__ R) {
  __shared__ float wrow[D];
  const int i = blockIdx.x, j = threadIdx.x;
  wrow[j] = W[i * D + j];
  __syncthreads();
  float acc = 0.f;
#pragma unroll 8
  for (int k = 0; k < D; ++k) acc = fmaf(wrow[k], X[k * D + j], acc);
  R[i * D + j] = (i == j ? 2.0f : 0.0f) - acc;
}

__global__ __launch_bounds__(256) void nr_mult(const float* __restrict__ X,
                                               const float* __restrict__ R,
                                               float* __restrict__ Y) {
  __shared__ float xrow[D];
  const int i = blockIdx.x, j = threadIdx.x;
  xrow[j] = X[i * D + j];
  __syncthreads();
  float acc = 0.f;
#pragma unroll 8
  for (int k = 0; k < D; ++k) acc = fmaf(xrow[k], R[k * D + j], acc);
  Y[i * D + j] = acc;
}

// ---------------------------------------------------------------------------
// W -> bf16
// ---------------------------------------------------------------------------
__global__ __launch_bounds__(256) void wconv(const float* __restrict__ W,
                                             u16* __restrict__ Wb) {
  const int i = blockIdx.x * 256 + threadIdx.x;
  Wb[i] = f2bf(W[i]);
}

// IW -> bf16, and bneg[col] = -(b . IW[col][:])
__global__ __launch_bounds__(256) void iwconv_bneg(const float* __restrict__ IW,
                                                   const float* __restrict__ bv,
                                                   u16* __restrict__ IWb,
                                                   float* __restrict__ bneg) {
  __shared__ float ws4[4];
  const int col = blockIdx.x, t = threadIdx.x;
  const float v = IW[col * D + t];
  IWb[col * D + t] = f2bf(v);
  float s = v * bv[t];
#pragma unroll
  for (int off = 32; off; off >>= 1) s += __shfl_xor(s, off, 64);
  if ((t & 63) == 0) ws4[t >> 6] = s;
  __syncthreads();
  if (t == 0) bneg[col] = -(ws4[0] + ws4[1] + ws4[2] + ws4[3]);
}

// ---------------------------------------------------------------------------
// Row squared-norms of p1/p2 (exact f32), written CLASS-MAJOR: n[c*1024+i].
// ---------------------------------------------------------------------------
__global__ __launch_bounds__(256) void norms12(const float* __restrict__ p1,
                                               const float* __restrict__ p2,
                                               float* __restrict__ n1,
                                               float* __restrict__ n2) {
  const int t = threadIdx.x, lr = t >> 6, l = t & 63;
  const size_t g = (size_t)blockIdx.x * 4 + lr;
  const size_t ci = ((g & 63) << 10) + (g >> 6);
  float4 v = *(const float4*)(p1 + g * D + l * 4);
  float s = fmaf(v.x, v.x, fmaf(v.y, v.y, fmaf(v.z, v.z, v.w * v.w)));
#pragma unroll
  for (int off = 32; off; off >>= 1) s += __shfl_xor(s, off, 64);
  if (l == 0) n1[ci] = s;
  float4 u = *(const float4*)(p2 + g * D + l * 4);
  float s2 = fmaf(u.x, u.x, fmaf(u.y, u.y, fmaf(u.z, u.z, u.w * u.w)));
#pragma unroll
  for (int off = 32; off; off >>= 1) s2 += __shfl_xor(s2, off, 64);
  if (l == 0) n2[ci] = s2;
}

// Row squared-norms of the bf16 F/Q buffers (already class-major).
__global__ __launch_bounds__(256) void norms_fq(const u16* __restrict__ Fb,
                                                const u16* __restrict__ Qb,
                                                float* __restrict__ nf,
                                                float* __restrict__ nq) {
  const int t = threadIdx.x, lr = t >> 6, l = t & 63;
  const size_t m = (size_t)blockIdx.x * 4 + lr;
  uint2 a = *(const uint2*)(Fb + m * D + l * 4);
  float x0 = bf2f(a.x & 0xFFFFu), x1 = bf2f(a.x >> 16);
  float x2 = bf2f(a.y & 0xFFFFu), x3 = bf2f(a.y >> 16);
  float s = fmaf(x0, x0, fmaf(x1, x1, fmaf(x2, x2, x3 * x3)));
#pragma unroll
  for (int off = 32; off; off >>= 1) s += __shfl_xor(s, off, 64);
  if (l == 0) nf[m] = s;
  uint2 b = *(const uint2*)(Qb + m * D + l * 4);
  float y0 = bf2f(b.x & 0xFFFFu), y1 = bf2f(b.x >> 16);
  float y2 = bf2f(b.y & 0xFFFFu), y3 = bf2f(b.y >> 16);
  float s2 = fmaf(y0, y0, fmaf(y1, y1, fmaf(y2, y2, y3 * y3)));
#pragma unroll
  for (int off = 32; off; off >>= 1) s2 += __shfl_xor(s2, off, 64);
  if (l == 0) nq[m] = s2;
}

// ---------------------------------------------------------------------------
// prep (MFMA): Out = bf16(A) @ Brows^T + bias, written CLASS-MAJOR bf16.
//   MODE 0: A=p1, Brows=Wb,  bias=b     -> F
//   MODE 1: A=p2, Brows=IWb, bias=bneg  -> Q   (bneg = -b@IW^T folds the -b)
// ---------------------------------------------------------------------------
#define PREP_LDS 131072
template <int MODE>
__global__ __launch_bounds__(256) void prep_kernel(const float* __restrict__ Ain,
                                                   const u16* __restrict__ Brows,
                                                   const float* __restrict__ bias,
                                                   u16* __restrict__ Out) {
  extern __shared__ char smem[];
  const int bid = blockIdx.x;
  const int it = bid >> 1, jh = bid & 1;
  const int tx = threadIdx.x, wid = tx >> 6, l = tx & 63;
  const int wm = wid >> 1, wn = wid & 1, l4 = l >> 4, lm = l & 15;

#pragma unroll
  for (int u = 0; u < 16; ++u) {
    const int ks = wid * 2 + (u >> 3), jf = u & 7;
    const u16* src = Brows + (size_t)(jh * 128 + jf * 16 + lm) * D + ks * 32 + l4 * 8;
    gload_lds16(src, smem + 65536 + (ks * 8 + jf) * 1024);
  }
  {
    const int r = tx >> 1, h = tx & 1;
    const float* arow = Ain + (size_t)(it * 128 + r) * D + h * 128;
#pragma unroll
    for (int q = 0; q < 4; ++q) {
      const int ks = h * 4 + q;
#pragma unroll
      for (int g = 0; g < 4; ++g) {
        float4 v0 = *(const float4*)(arow + q * 32 + g * 8);
        float4 v1 = *(const float4*)(arow + q * 32 + g * 8 + 4);
        uint4 w;
        w.x = pk2(v0.x, v0.y); w.y = pk2(v0.z, v0.w);
        w.z = pk2(v1.x, v1.y); w.w = pk2(v1.z, v1.w);
        *(uint4*)(smem + (ks * 8 + (r >> 4)) * 1024 + ((r & 15) + g * 16) * 16) = w;
      }
    }
  }
  __syncthreads();

  const bfv8* lds8 = (const bfv8*)smem;
  f32x4 acc[4][4];
#pragma unroll
  for (int m = 0; m < 4; ++m)
#pragma unroll
    for (int n = 0; n < 4; ++n) acc[m][n] = f32x4{0.f, 0.f, 0.f, 0.f};
#pragma unroll
  for (int ks = 0; ks < 8; ++ks) {
    bfv8 a[4], bb[4];
#pragma unroll
    for (int m = 0; m < 4; ++m) a[m] = lds8[(ks * 8 + wm * 4 + m) * 64 + l];
#pragma unroll
    for (int n = 0; n < 4; ++n) bb[n] = lds8[4096 + (ks * 8 + wn * 4 + n) * 64 + l];
#pragma unroll
    for (int m = 0; m < 4; ++m)
#pragma unroll
      for (int n = 0; n < 4; ++n)
        acc[m][n] = __builtin_amdgcn_mfma_f32_16x16x32_bf16(a[m], bb[n], acc[m][n], 0, 0, 0);
  }

  float bvv[4];
#pragma unroll
  for (int n = 0; n < 4; ++n) bvv[n] = bias[jh * 128 + wn * 64 + n * 16 + lm];
#pragma unroll
  for (int m = 0; m < 4; ++m)
#pragma unroll
    for (int rr = 0; rr < 4; ++rr) {
      const int g = it * 128 + wm * 64 + m * 16 + l4 * 4 + rr;
      const size_t orow = (size_t)(((g & 63) << 10) | (g >> 6)) * D;
#pragma unroll
      for (int n = 0; n < 4; ++n) {
        const int col = jh * 128 + wn * 64 + n * 16 + lm;
        Out[orow + col] = f2bf(acc[m][n][rr] + bvv[n]);
      }
    }
}

// ---------------------------------------------------------------------------
// dist (MFMA): per (c, dir, i-tile 128): loop 8 j-tiles of 128, K=256 bf16
// MFMA GEMM; fused dist = na+nb-2*dot and running min; block-partial sums.
// ---------------------------------------------------------------------------
#define DIST_LDS 132160
__global__ __launch_bounds__(256) void dist_kernel(
    const float* __restrict__ p1, const float* __restrict__ p2,
    const u16* __restrict__ Qb, const u16* __restrict__ Fb,
    const float* __restrict__ n1, const float* __restrict__ n2,
    const float* __restrict__ nq, const float* __restrict__ nf,
    float* __restrict__ partial) {
  extern __shared__ char smem[];
  const int bid = blockIdx.x;
  const int lb = (bid & 7) * 128 + (bid >> 3);   // XCD-chunked swizzle
  const int c = lb >> 4, dir = (lb >> 3) & 1, it = lb & 7;
  const float* Ain = dir ? p2 : p1;
  const u16* Bin = dir ? Fb : Qb;
  const float* nA = dir ? n2 : n1;
  const float* nB = dir ? nf : nq;
  const int tx = threadIdx.x, wid = tx >> 6, l = tx & 63;
  const int wm = wid >> 1, wn = wid & 1, l4 = l >> 4, lm = l & 15;

  auto issue_b = [&](int half, int jt) {
    const size_t base = ((size_t)(c << 10) + jt * 128) * D;
#pragma unroll
    for (int jf = 0; jf < 8; ++jf) {
      const u16* src = Bin + base + (size_t)(jf * 16 + lm) * D
                       + half * 128 + wid * 32 + l4 * 8;
      gload_lds16(src, smem + 65536 + half * 32768 + (wid * 8 + jf) * 1024);
    }
  };

  issue_b(0, 0);
  {
    const int r = tx >> 1, h = tx & 1;
    const float* arow = Ain + ((size_t)(it * 128 + r) * NC + c) * D + h * 128;
#pragma unroll
    for (int q = 0; q < 4; ++q) {
      const int ks = h * 4 + q;
#pragma unroll
      for (int g = 0; g < 4; ++g) {
        float4 v0 = *(const float4*)(arow + q * 32 + g * 8);
        float4 v1 = *(const float4*)(arow + q * 32 + g * 8 + 4);
        uint4 w;
        w.x = pk2(v0.x, v0.y); w.y = pk2(v0.z, v0.w);
        w.z = pk2(v1.x, v1.y); w.w = pk2(v1.z, v1.w);
        *(uint4*)(smem + (ks * 8 + (r >> 4)) * 1024 + ((r & 15) + g * 16) * 16) = w;
      }
    }
  }
  float na[4][4];
#pragma unroll
  for (int m = 0; m < 4; ++m)
#pragma unroll
    for (int rr = 0; rr < 4; ++rr)
      na[m][rr] = nA[(c << 10) + it * 128 + wm * 64 + m * 16 + l4 * 4 + rr];
  float minv[4][4];
#pragma unroll
  for (int m = 0; m < 4; ++m)
#pragma unroll
    for (int rr = 0; rr < 4; ++rr) minv[m][rr] = 3.0e38f;
  __syncthreads();

  const bfv8* lds8 = (const bfv8*)smem;
  for (int jt = 0; jt < 8; ++jt) {
    f32x4 acc[4][4];
#pragma unroll
    for (int m = 0; m < 4; ++m)
#pragma unroll
      for (int n = 0; n < 4; ++n) acc[m][n] = f32x4{0.f, 0.f, 0.f, 0.f};
    float nbv[4];
#pragma unroll
    for (int n = 0; n < 4; ++n)
      nbv[n] = nB[(c << 10) + jt * 128 + wn * 64 + n * 16 + lm];

    issue_b(1, jt);
#pragma unroll
    for (int ks = 0; ks < 4; ++ks) {
      bfv8 a[4], bb[4];
#pragma unroll
      for (int m = 0; m < 4; ++m) a[m] = lds8[(ks * 8 + wm * 4 + m) * 64 + l];
#pragma unroll
      for (int n = 0; n < 4; ++n) bb[n] = lds8[4096 + (ks * 8 + wn * 4 + n) * 64 + l];
#pragma unroll
      for (int m = 0; m < 4; ++m)
#pragma unroll
        for (int n = 0; n < 4; ++n)
          acc[m][n] = __builtin_amdgcn_mfma_f32_16x16x32_bf16(a[m], bb[n], acc[m][n], 0, 0, 0);
    }
    __syncthreads();
    if (jt < 7) issue_b(0, jt + 1);
#pragma unroll
    for (int ks = 4; ks < 8; ++ks) {
      bfv8 a[4], bb[4];
#pragma unroll
      for (int m = 0; m < 4; ++m) a[m] = lds8[(ks * 8 + wm * 4 + m) * 64 + l];
#pragma unroll
      for (int n = 0; n < 4; ++n)
        bb[n] = lds8[6144 + ((ks - 4) * 8 + wn * 4 + n) * 64 + l];
#pragma unroll
      for (int m = 0; m < 4; ++m)
#pragma unroll
        for (int n = 0; n < 4; ++n)
          acc[m][n] = __builtin_amdgcn_mfma_f32_16x16x32_bf16(a[m], bb[n], acc[m][n], 0, 0, 0);
    }
#pragma unroll
    for (int m = 0; m < 4; ++m)
#pragma unroll
      for (int n = 0; n < 4; ++n)
#pragma unroll
        for (int rr = 0; rr < 4; ++rr) {
          const float dd = na[m][rr] + nbv[n] - 2.0f * acc[m][n][rr];
          minv[m][rr] = fminf(minv[m][rr], dd);
        }
    __syncthreads();
  }

  float* red = (float*)(smem + 131072);
#pragma unroll
  for (int m = 0; m < 4; ++m)
#pragma unroll
    for (int rr = 0; rr < 4; ++rr) {
      float mm = minv[m][rr];
      mm = fminf(mm, __shfl_xor(mm, 1, 64));
      mm = fminf(mm, __shfl_xor(mm, 2, 64));
      mm = fminf(mm, __shfl_xor(mm, 4, 64));
      mm = fminf(mm, __shfl_xor(mm, 8, 64));
      if (lm == 0) red[wn * 128 + wm * 64 + m * 16 + l4 * 4 + rr] = mm;
    }
  __syncthreads();
  if (tx < 128) {
    float v = fminf(red[tx], red[128 + tx]);
#pragma unroll
    for (int off = 32; off; off >>= 1) v += __shfl_xor(v, off, 64);
    if ((tx & 63) == 0) red[256 + (tx >> 6)] = v;
  }
  __syncthreads();
  if (tx == 0) partial[lb] = red[256] + red[257];
}

__global__ void finalize_kernel(const float* __restrict__ partial,
                                float* __restrict__ out) {
  const int tx = threadIdx.x;
  if (tx >= 128) return;
  const int dir = tx >> 6, c = tx & 63;
  float s = 0.f;
#pragma unroll
  for (int it = 0; it < 8; ++it) s += partial[(c << 4) | (dir << 3) | it];
  out[dir * 64 + c] = s * (1.0f / 1024.0f);
}

extern "C" void kernel_launch(void* const* d_in, const int* in_sizes, int n_in,
                              void* d_out, int out_size, void* d_ws, size_t ws_size,
                              hipStream_t stream) {
  const float* p1 = (const float*)d_in[0];
  const float* p2 = (const float*)d_in[1];
  const float* W  = (const float*)d_in[2];
  const float* bv = (const float*)d_in[3];
  float* out = (float*)d_out;
  char* ws = (char*)d_ws;
  float* IWa  = (float*)(ws + 0);                // 256 KB
  float* Rt   = (float*)(ws + (256 << 10));      // 256 KB
  float* IWc  = (float*)(ws + (512 << 10));      // 256 KB
  float* n1   = (float*)(ws + (768 << 10));      // 256 KB each
  float* n2   = (float*)(ws + (1024 << 10));
  float* nq   = (float*)(ws + (1280 << 10));
  float* nf   = (float*)(ws + (1536 << 10));
  float* partial = (float*)(ws + (1792 << 10));  // 4 KB
  float* bneg = (float*)(ws + (1800 << 10));     // 1 KB
  u16* Wb  = (u16*)(ws + (1808 << 10));          // 128 KB
  u16* IWb = (u16*)(ws + (1936 << 10));          // 128 KB
  u16* Fb  = (u16*)(ws + (2112 << 10));                  // 32 MB
  u16* Qb  = (u16*)(ws + (2112 << 10) + (32u << 20));    // 32 MB

  hipFuncSetAttribute((const void*)prep_kernel<0>,
                      hipFuncAttributeMaxDynamicSharedMemorySize, PREP_LDS);
  hipFuncSetAttribute((const void*)prep_kernel<1>,
                      hipFuncAttributeMaxDynamicSharedMemorySize, PREP_LDS);
  hipFuncSetAttribute((const void*)dist_kernel,
                      hipFuncAttributeMaxDynamicSharedMemorySize, DIST_LDS);

  norms12<<<16384, 256, 0, stream>>>(p1, p2, n1, n2);
  wconv<<<256, 256, 0, stream>>>(W, Wb);
  gj_inverse<<<1, 512, 0, stream>>>(W, IWa);
  nr_residual<<<256, 256, 0, stream>>>(W, IWa, Rt);
  nr_mult<<<256, 256, 0, stream>>>(IWa, Rt, IWc);
  nr_residual<<<256, 256, 0, stream>>>(W, IWc, Rt);
  nr_mult<<<256, 256, 0, stream>>>(IWc, Rt, IWa);
  iwconv_bneg<<<256, 256, 0, stream>>>(IWa, bv, IWb, bneg);
  prep_kernel<0><<<1024, 256, PREP_LDS, stream>>>(p1, Wb, bv, Fb);
  prep_kernel<1><<<1024, 256, PREP_LDS, stream>>>(p2, IWb, bneg, Qb);
  norms_fq<<<16384, 256, 0, stream>>>(Fb, Qb, nf, nq);
  dist_kernel<<<1024, 256, DIST_LDS, stream>>>(p1, p2, Qb, Fb, n1, n2, nq, nf, partial);
  finalize_kernel<<<1, 128, 0, stream>>>(partial, out);
}